// Round 1
// baseline (777.169 us; speedup 1.0000x reference)
//
#include <hip/hip_runtime.h>

#define H 128

// ---------------- graph preprocessing ----------------

__global__ void count_k(const int* __restrict__ dst, int* __restrict__ cnt, int E) {
    int e = blockIdx.x * blockDim.x + threadIdx.x;
    if (e < E) atomicAdd(&cnt[dst[e]], 1);
}

__global__ void dinv_k(const int* __restrict__ cnt, float* __restrict__ dinv, int n) {
    int i = blockIdx.x * blockDim.x + threadIdx.x;
    if (i < n) dinv[i] = 1.0f / sqrtf((float)(cnt[i] + 1));  // +1 = self loop
}

__global__ __launch_bounds__(256) void scan_partial_k(const int* __restrict__ cnt,
                                                      int* __restrict__ part, int n) {
    __shared__ int sm[256];
    int base = blockIdx.x * 1024 + threadIdx.x * 4;
    int s = 0;
    #pragma unroll
    for (int j = 0; j < 4; ++j) { int i = base + j; if (i < n) s += cnt[i]; }
    sm[threadIdx.x] = s;
    __syncthreads();
    for (int off = 128; off > 0; off >>= 1) {
        if (threadIdx.x < off) sm[threadIdx.x] += sm[threadIdx.x + off];
        __syncthreads();
    }
    if (threadIdx.x == 0) part[blockIdx.x] = sm[0];
}

__global__ void scan_part_k(int* part, int nb) {
    if (blockIdx.x == 0 && threadIdx.x == 0) {
        int run = 0;
        for (int b = 0; b < nb; ++b) { int v = part[b]; part[b] = run; run += v; }
    }
}

// writes exclusive-scan offsets to offs[], and also copies them into cnt[] (reused as fill cursor)
__global__ __launch_bounds__(256) void scan_final_k(int* __restrict__ cnt, const int* __restrict__ part,
                                                    int* __restrict__ offs, int n, int Etot) {
    __shared__ int sm[256];
    int tid = threadIdx.x;
    int base = blockIdx.x * 1024 + tid * 4;
    int v[4]; int s = 0;
    #pragma unroll
    for (int j = 0; j < 4; ++j) { int i = base + j; v[j] = (i < n) ? cnt[i] : 0; s += v[j]; }
    sm[tid] = s;
    __syncthreads();
    for (int off = 1; off < 256; off <<= 1) {
        int t = (tid >= off) ? sm[tid - off] : 0;
        __syncthreads();
        sm[tid] += t;
        __syncthreads();
    }
    int excl = sm[tid] - s + part[blockIdx.x];
    #pragma unroll
    for (int j = 0; j < 4; ++j) {
        int i = base + j;
        if (i < n) { offs[i] = excl; cnt[i] = excl; excl += v[j]; }
    }
    if (blockIdx.x == 0 && tid == 0) offs[n] = Etot;
}

__global__ void fill_k(const int* __restrict__ src, const int* __restrict__ dst,
                       int* __restrict__ cursor, int* __restrict__ csr, int E) {
    int e = blockIdx.x * blockDim.x + threadIdx.x;
    if (e < E) {
        int d = dst[e];
        int p = atomicAdd(&cursor[d], 1);
        csr[p] = src[e];
    }
}

// ---------------- layer 1 (scalar input feature) ----------------

__global__ void s_k(const float* __restrict__ x, const float* __restrict__ dinv,
                    float* __restrict__ s, int n) {
    int i = blockIdx.x * blockDim.x + threadIdx.x;
    if (i < n) s[i] = x[i] * dinv[i];
}

__global__ void agg1_k(const float* __restrict__ s, const int* __restrict__ offs,
                       const int* __restrict__ csr, const float* __restrict__ dinv,
                       float* __restrict__ t, int n) {
    int i = blockIdx.x * blockDim.x + threadIdx.x;
    if (i >= n) return;
    float sum = s[i];                       // self loop
    int e0 = offs[i], e1 = offs[i + 1];
    for (int p = e0; p < e1; ++p) sum += s[csr[p]];
    t[i] = sum * dinv[i];
}

__global__ void expand1_k(const float* __restrict__ t, const float* __restrict__ W1,
                          const float* __restrict__ b1, float* __restrict__ h, int n) {
    int idx = blockIdx.x * blockDim.x + threadIdx.x;
    int node = idx >> 5, l = idx & 31;
    if (node >= n) return;
    float tv = t[node];
    float4 w = ((const float4*)W1)[l];
    float4 b = ((const float4*)b1)[l];
    float4 o;
    o.x = fmaxf(fmaf(tv, w.x, b.x), 0.f);
    o.y = fmaxf(fmaf(tv, w.y, b.y), 0.f);
    o.z = fmaxf(fmaf(tv, w.z, b.z), 0.f);
    o.w = fmaxf(fmaf(tv, w.w, b.w), 0.f);
    ((float4*)h)[(size_t)node * 32 + l] = o;
}

// ---------------- generic 128-wide GEMM: out = act(in @ W [*scale_row] [+bias]) ----------------
// block: 256 threads; 128 rows/block; each thread: 4 rows x 16 cols; W staged in LDS (64 KB)

__global__ __launch_bounds__(256) void gemm_k(const float* __restrict__ in, const float* __restrict__ W,
                                              const float* __restrict__ bias, const float* __restrict__ scale,
                                              float* __restrict__ out, int n, int relu) {
    __shared__ float Wl[H * H];
    {
        const float4* Wv = (const float4*)W;
        float4* Wd = (float4*)Wl;
        for (int i = threadIdx.x; i < H * H / 4; i += 256) Wd[i] = Wv[i];
    }
    __syncthreads();
    const int cc = threadIdx.x & 7;     // 8 col groups of 16
    const int rg = threadIdx.x >> 3;    // 32 row groups of 4
    const int c0 = cc * 16;
    const int row0 = blockIdx.x * 128 + rg * 4;

    const float* p[4];
    #pragma unroll
    for (int r = 0; r < 4; ++r) {
        int rr = row0 + r; if (rr > n - 1) rr = n - 1;
        p[r] = in + (size_t)rr * H;
    }

    float acc[4][16];
    #pragma unroll
    for (int r = 0; r < 4; ++r)
        #pragma unroll
        for (int j = 0; j < 16; ++j) acc[r][j] = 0.f;

    for (int k4 = 0; k4 < H / 4; ++k4) {
        float4 a[4];
        #pragma unroll
        for (int r = 0; r < 4; ++r) a[r] = *(const float4*)(p[r] + k4 * 4);
        const float* wbase = Wl + (k4 * 4) * H + c0;
        #pragma unroll
        for (int kk = 0; kk < 4; ++kk) {
            float w[16];
            *(float4*)(w + 0)  = *(const float4*)(wbase + kk * H + 0);
            *(float4*)(w + 4)  = *(const float4*)(wbase + kk * H + 4);
            *(float4*)(w + 8)  = *(const float4*)(wbase + kk * H + 8);
            *(float4*)(w + 12) = *(const float4*)(wbase + kk * H + 12);
            float av[4];
            #pragma unroll
            for (int r = 0; r < 4; ++r) av[r] = ((const float*)&a[r])[kk];
            #pragma unroll
            for (int r = 0; r < 4; ++r)
                #pragma unroll
                for (int j = 0; j < 16; ++j)
                    acc[r][j] = fmaf(av[r], w[j], acc[r][j]);
        }
    }

    #pragma unroll
    for (int r = 0; r < 4; ++r) {
        int row = row0 + r;
        if (row < n) {
            float sc = scale ? scale[row] : 1.0f;
            float* orow = out + (size_t)row * H + c0;
            #pragma unroll
            for (int j4 = 0; j4 < 4; ++j4) {
                float4 o;
                o.x = acc[r][j4 * 4 + 0] * sc;
                o.y = acc[r][j4 * 4 + 1] * sc;
                o.z = acc[r][j4 * 4 + 2] * sc;
                o.w = acc[r][j4 * 4 + 3] * sc;
                if (bias) {
                    o.x += bias[c0 + j4 * 4 + 0];
                    o.y += bias[c0 + j4 * 4 + 1];
                    o.z += bias[c0 + j4 * 4 + 2];
                    o.w += bias[c0 + j4 * 4 + 3];
                }
                if (relu) {
                    o.x = fmaxf(o.x, 0.f); o.y = fmaxf(o.y, 0.f);
                    o.z = fmaxf(o.z, 0.f); o.w = fmaxf(o.w, 0.f);
                }
                *(float4*)(orow + j4 * 4) = o;
            }
        }
    }
}

// ---------------- vector aggregation: h' = relu(dinv*(hs[self] + sum_in hs[src]) + b) ----------------
// 32 threads per node, float4 per thread -> 512B coalesced row gathers

__global__ __launch_bounds__(256) void aggregate_k(const float* __restrict__ hs, const int* __restrict__ offs,
                                                   const int* __restrict__ csr, const float* __restrict__ dinv,
                                                   const float* __restrict__ bias, float* __restrict__ hout, int n) {
    int node = blockIdx.x * 8 + (threadIdx.x >> 5);
    int l = threadIdx.x & 31;
    if (node >= n) return;
    const float4* hs4 = (const float4*)hs;
    float4 sum = hs4[(size_t)node * 32 + l];        // self loop
    int e0 = offs[node], e1 = offs[node + 1];
    for (int p = e0; p < e1; ++p) {
        int srcn = csr[p];
        float4 v = hs4[(size_t)srcn * 32 + l];
        sum.x += v.x; sum.y += v.y; sum.z += v.z; sum.w += v.w;
    }
    float d = dinv[node];
    float4 b = ((const float4*)bias)[l];
    float4 o;
    o.x = fmaxf(fmaf(sum.x, d, b.x), 0.f);
    o.y = fmaxf(fmaf(sum.y, d, b.y), 0.f);
    o.z = fmaxf(fmaf(sum.z, d, b.z), 0.f);
    o.w = fmaxf(fmaf(sum.w, d, b.w), 0.f);
    ((float4*)hout)[(size_t)node * 32 + l] = o;
}

// ---------------- pooling ----------------

__global__ void gstart_k(const int* __restrict__ batch, int* __restrict__ start, int n, int G) {
    int i = blockIdx.x * blockDim.x + threadIdx.x;
    if (i >= n) return;
    int b = batch[i];
    int prev = (i == 0) ? -1 : batch[i - 1];
    for (int g = prev + 1; g <= b; ++g) start[g] = i;
    if (i == n - 1) { for (int g = b + 1; g <= G; ++g) start[g] = n; }
}

__global__ __launch_bounds__(128) void pool_k(const float* __restrict__ h, const int* __restrict__ start,
                                              float* __restrict__ P, int G) {
    int g = blockIdx.x, f = threadIdx.x;
    int s0 = start[g], s1 = start[g + 1];
    float sum = 0.f;
    for (int i = s0; i < s1; ++i) sum += h[(size_t)i * H + f];
    float c = (float)(s1 - s0); if (c < 1.f) c = 1.f;
    P[(size_t)g * H + f] = sum / c;
}

// ---------------- final dot: out[g] = g2[g] . Wl3 + bl3 ----------------

__global__ __launch_bounds__(256) void outdot_k(const float* __restrict__ g2, const float* __restrict__ Wl3,
                                                const float* __restrict__ bl3, float* __restrict__ out, int G) {
    int gi = blockIdx.x * 4 + (threadIdx.x >> 6);
    int lane = threadIdx.x & 63;
    if (gi >= G) return;
    const float* row = g2 + (size_t)gi * H;
    float v = fmaf(row[lane], Wl3[lane], row[64 + lane] * Wl3[64 + lane]);
    for (int off = 32; off > 0; off >>= 1) v += __shfl_down(v, off);
    if (lane == 0) out[gi] = v + bl3[0];
}

// ---------------- launch ----------------

extern "C" void kernel_launch(void* const* d_in, const int* in_sizes, int n_in,
                              void* d_out, int out_size, void* d_ws, size_t ws_size,
                              hipStream_t stream) {
    const float* x     = (const float*)d_in[0];
    const int*   ei    = (const int*)d_in[1];
    const int*   batch = (const int*)d_in[2];
    const float* W1  = (const float*)d_in[3];  const float* b1  = (const float*)d_in[4];
    const float* W2  = (const float*)d_in[5];  const float* b2  = (const float*)d_in[6];
    const float* W3  = (const float*)d_in[7];  const float* b3  = (const float*)d_in[8];
    const float* Wl1 = (const float*)d_in[9];  const float* bl1 = (const float*)d_in[10];
    const float* Wl2 = (const float*)d_in[11]; const float* bl2 = (const float*)d_in[12];
    const float* Wl3 = (const float*)d_in[13]; const float* bl3 = (const float*)d_in[14];

    const int N = in_sizes[0];
    const int E = in_sizes[1] / 2;
    const int G = out_size;
    const int* srcp = ei;
    const int* dstp = ei + E;

    // workspace carve (all 256B aligned)
    char* w = (char*)d_ws;
    size_t off = 0;
    auto alloc = [&](size_t bytes) -> void* {
        void* p = w + off;
        off += (bytes + 255) & ~(size_t)255;
        return p;
    };
    int*   cnt    = (int*)alloc((size_t)N * 4);          // counts, then fill cursor
    int*   offs   = (int*)alloc((size_t)(N + 1) * 4);
    int*   part   = (int*)alloc(512 * 4);
    int*   csr    = (int*)alloc((size_t)E * 4);
    int*   gstart = (int*)alloc((size_t)(G + 1) * 4);
    float* dinv   = (float*)alloc((size_t)N * 4);
    float* sbuf   = (float*)alloc((size_t)N * 4);
    float* tbuf   = (float*)alloc((size_t)N * 4);
    float* A      = (float*)alloc((size_t)N * H * 4);    // h
    float* B      = (float*)alloc((size_t)N * H * 4);    // hs
    float* P      = (float*)alloc((size_t)G * H * 4);
    float* Q      = (float*)alloc((size_t)G * H * 4);
    float* R      = (float*)alloc((size_t)G * H * 4);
    (void)ws_size; (void)n_in;

    const int nsb = (N + 1023) / 1024;   // scan blocks

    // --- graph preprocessing ---
    hipMemsetAsync(cnt, 0, (size_t)N * 4, stream);
    count_k<<<(E + 255) / 256, 256, 0, stream>>>(dstp, cnt, E);
    dinv_k<<<(N + 255) / 256, 256, 0, stream>>>(cnt, dinv, N);
    scan_partial_k<<<nsb, 256, 0, stream>>>(cnt, part, N);
    scan_part_k<<<1, 1, 0, stream>>>(part, nsb);
    scan_final_k<<<nsb, 256, 0, stream>>>(cnt, part, offs, N, E);
    fill_k<<<(E + 255) / 256, 256, 0, stream>>>(srcp, dstp, cnt, csr, E);

    // --- layer 1 (scalar feature) ---
    s_k<<<(N + 255) / 256, 256, 0, stream>>>(x, dinv, sbuf, N);
    agg1_k<<<(N + 255) / 256, 256, 0, stream>>>(sbuf, offs, csr, dinv, tbuf, N);
    expand1_k<<<((size_t)N * 32 + 255) / 256, 256, 0, stream>>>(tbuf, W1, b1, A, N);

    // --- layer 2 ---
    gemm_k<<<(N + 127) / 128, 256, 0, stream>>>(A, W2, nullptr, dinv, B, N, 0);
    aggregate_k<<<(N + 7) / 8, 256, 0, stream>>>(B, offs, csr, dinv, b2, A, N);

    // --- layer 3 ---
    gemm_k<<<(N + 127) / 128, 256, 0, stream>>>(A, W3, nullptr, dinv, B, N, 0);
    aggregate_k<<<(N + 7) / 8, 256, 0, stream>>>(B, offs, csr, dinv, b3, A, N);

    // --- mean pool ---
    gstart_k<<<(N + 255) / 256, 256, 0, stream>>>(batch, gstart, N, G);
    pool_k<<<G, 128, 0, stream>>>(A, gstart, P, G);

    // --- MLP head ---
    gemm_k<<<(G + 127) / 128, 256, 0, stream>>>(P, Wl1, bl1, nullptr, Q, G, 1);
    gemm_k<<<(G + 127) / 128, 256, 0, stream>>>(Q, Wl2, bl2, nullptr, R, G, 1);
    outdot_k<<<(G + 3) / 4, 256, 0, stream>>>(R, Wl3, bl3, (float*)d_out, G);
}

// Round 2
// 602.453 us; speedup vs baseline: 1.2900x; 1.2900x over previous
//
#include <hip/hip_runtime.h>

#define H 128
#define SHIFT 10            // nodes per coarse bucket = 1024
#define BN 1024
#define MAXNB 128           // max coarse buckets (N <= 131072)
#define CHUNK 4096          // edges per scatter block

// ============ graph build: two-level counting sort (no random 4B scatters) ============
// Packing: N=100000 < 2^17, BN=1024 -> record = (local_node<<17)|src fits u32.

__global__ __launch_bounds__(256) void hist_coarse_k(const int* __restrict__ dst,
                                                     int* __restrict__ coarse, int E, int NBv) {
    __shared__ int h[MAXNB];
    int tid = threadIdx.x;
    if (tid < MAXNB) h[tid] = 0;
    __syncthreads();
    for (int e = blockIdx.x * blockDim.x + tid; e < E; e += gridDim.x * blockDim.x)
        atomicAdd(&h[dst[e] >> SHIFT], 1);
    __syncthreads();
    if (tid < NBv && h[tid] > 0) atomicAdd(&coarse[tid], h[tid]);
}

__global__ void scan_coarse_k(const int* __restrict__ coarse, int* __restrict__ cbase,
                              int* __restrict__ gcur, int* __restrict__ offs,
                              int NBv, int N, int E) {
    if (blockIdx.x == 0 && threadIdx.x == 0) {
        int run = 0;
        for (int b = 0; b < NBv; ++b) { int v = coarse[b]; cbase[b] = run; gcur[b] = run; run += v; }
        cbase[NBv] = run;
        offs[N] = E;
    }
}

__global__ __launch_bounds__(256) void scatter_pairs_k(const int* __restrict__ src,
                                                       const int* __restrict__ dst,
                                                       int* __restrict__ gcur,
                                                       unsigned* __restrict__ pairbuf,
                                                       int E, int NBv) {
    __shared__ unsigned stage[CHUNK];
    __shared__ unsigned char stb[CHUNK];
    __shared__ int hist[MAXNB], basel[MAXNB], cur[MAXNB], gbase[MAXNB];
    __shared__ int total;
    int tid = threadIdx.x;
    int base = blockIdx.x * CHUNK;

    int mysrc[16], mydst[16];
    #pragma unroll
    for (int i = 0; i < 16; ++i) {
        int e = base + i * 256 + tid;
        if (e < E) { mysrc[i] = src[e]; mydst[i] = dst[e]; } else mydst[i] = -1;
    }
    if (tid < MAXNB) hist[tid] = 0;
    __syncthreads();
    #pragma unroll
    for (int i = 0; i < 16; ++i)
        if (mydst[i] >= 0) atomicAdd(&hist[mydst[i] >> SHIFT], 1);
    __syncthreads();
    if (tid == 0) {
        int run = 0;
        for (int b = 0; b < NBv; ++b) { basel[b] = run; run += hist[b]; }
        total = run;
    }
    __syncthreads();
    if (tid < NBv) {
        cur[tid] = basel[tid];
        if (hist[tid] > 0) gbase[tid] = atomicAdd(&gcur[tid], hist[tid]);
    }
    __syncthreads();
    #pragma unroll
    for (int i = 0; i < 16; ++i)
        if (mydst[i] >= 0) {
            int b = mydst[i] >> SHIFT;
            int slot = atomicAdd(&cur[b], 1);
            stage[slot] = ((unsigned)(mydst[i] & (BN - 1)) << 17) | (unsigned)mysrc[i];
            stb[slot] = (unsigned char)b;
        }
    __syncthreads();
    for (int s = tid; s < total; s += 256) {
        int b = stb[s];
        pairbuf[gbase[b] + (s - basel[b])] = stage[s];   // contiguous runs -> full-line writes
    }
}

// one block per coarse bucket: LDS histogram + scan -> offs/dinv, then in-bucket scatter (L2-local)
__global__ __launch_bounds__(512) void build_csr_k(const unsigned* __restrict__ pairbuf,
                                                   const int* __restrict__ cbase,
                                                   int* __restrict__ offs, float* __restrict__ dinv,
                                                   int* __restrict__ csr, int N) {
    __shared__ int hist[BN];
    __shared__ int cur[BN];
    __shared__ int ps[512];
    int b = blockIdx.x, tid = threadIdx.x;
    int node0 = b << SHIFT;
    int e0 = cbase[b], e1 = cbase[b + 1];
    hist[tid] = 0; hist[tid + 512] = 0;
    __syncthreads();
    for (int p = e0 + tid; p < e1; p += 512)
        atomicAdd(&hist[pairbuf[p] >> 17], 1);
    __syncthreads();
    int v0 = hist[2 * tid], v1 = hist[2 * tid + 1];
    int pairsum = v0 + v1;
    ps[tid] = pairsum;
    __syncthreads();
    for (int off = 1; off < 512; off <<= 1) {
        int t = (tid >= off) ? ps[tid - off] : 0;
        __syncthreads();
        ps[tid] += t;
        __syncthreads();
    }
    int g0 = e0 + ps[tid] - pairsum;     // exclusive prefix -> global csr offset of node 2*tid
    int n0 = node0 + 2 * tid, n1 = n0 + 1;
    if (n0 < N) { offs[n0] = g0;      dinv[n0] = rsqrtf((float)(v0 + 1)); }
    if (n1 < N) { offs[n1] = g0 + v0; dinv[n1] = rsqrtf((float)(v1 + 1)); }
    cur[2 * tid] = g0; cur[2 * tid + 1] = g0 + v0;
    __syncthreads();
    for (int p = e0 + tid; p < e1; p += 512) {
        unsigned v = pairbuf[p];
        int pos = atomicAdd(&cur[v >> 17], 1);
        csr[pos] = (int)(v & 0x1FFFFu);
    }
}

// ---------------- layer 1 (scalar input feature) ----------------

__global__ void s_k(const float* __restrict__ x, const float* __restrict__ dinv,
                    float* __restrict__ s, int n) {
    int i = blockIdx.x * blockDim.x + threadIdx.x;
    if (i < n) s[i] = x[i] * dinv[i];
}

__global__ void agg1_k(const float* __restrict__ s, const int* __restrict__ offs,
                       const int* __restrict__ csr, const float* __restrict__ dinv,
                       float* __restrict__ t, int n) {
    int i = blockIdx.x * blockDim.x + threadIdx.x;
    if (i >= n) return;
    float sum = s[i];                       // self loop
    int e0 = offs[i], e1 = offs[i + 1];
    float a0 = 0.f, a1 = 0.f, a2 = 0.f, a3 = 0.f;
    int p = e0;
    for (; p + 4 <= e1; p += 4) {
        a0 += s[csr[p]]; a1 += s[csr[p + 1]]; a2 += s[csr[p + 2]]; a3 += s[csr[p + 3]];
    }
    for (; p < e1; ++p) sum += s[csr[p]];
    sum += (a0 + a1) + (a2 + a3);
    t[i] = sum * dinv[i];
}

__global__ void expand1_k(const float* __restrict__ t, const float* __restrict__ W1,
                          const float* __restrict__ b1, float* __restrict__ h, int n) {
    int idx = blockIdx.x * blockDim.x + threadIdx.x;
    int node = idx >> 5, l = idx & 31;
    if (node >= n) return;
    float tv = t[node];
    float4 w = ((const float4*)W1)[l];
    float4 b = ((const float4*)b1)[l];
    float4 o;
    o.x = fmaxf(fmaf(tv, w.x, b.x), 0.f);
    o.y = fmaxf(fmaf(tv, w.y, b.y), 0.f);
    o.z = fmaxf(fmaf(tv, w.z, b.z), 0.f);
    o.w = fmaxf(fmaf(tv, w.w, b.w), 0.f);
    ((float4*)h)[(size_t)node * 32 + l] = o;
}

// ---------------- generic 128-wide GEMM: out = act(in @ W [*scale_row] [+bias]) ----------------

__global__ __launch_bounds__(256) void gemm_k(const float* __restrict__ in, const float* __restrict__ W,
                                              const float* __restrict__ bias, const float* __restrict__ scale,
                                              float* __restrict__ out, int n, int relu) {
    __shared__ float Wl[H * H];
    {
        const float4* Wv = (const float4*)W;
        float4* Wd = (float4*)Wl;
        for (int i = threadIdx.x; i < H * H / 4; i += 256) Wd[i] = Wv[i];
    }
    __syncthreads();
    const int cc = threadIdx.x & 7;
    const int rg = threadIdx.x >> 3;
    const int c0 = cc * 16;
    const int row0 = blockIdx.x * 128 + rg * 4;

    const float* p[4];
    #pragma unroll
    for (int r = 0; r < 4; ++r) {
        int rr = row0 + r; if (rr > n - 1) rr = n - 1;
        p[r] = in + (size_t)rr * H;
    }

    float acc[4][16];
    #pragma unroll
    for (int r = 0; r < 4; ++r)
        #pragma unroll
        for (int j = 0; j < 16; ++j) acc[r][j] = 0.f;

    for (int k4 = 0; k4 < H / 4; ++k4) {
        float4 a[4];
        #pragma unroll
        for (int r = 0; r < 4; ++r) a[r] = *(const float4*)(p[r] + k4 * 4);
        const float* wbase = Wl + (k4 * 4) * H + c0;
        #pragma unroll
        for (int kk = 0; kk < 4; ++kk) {
            float w[16];
            *(float4*)(w + 0)  = *(const float4*)(wbase + kk * H + 0);
            *(float4*)(w + 4)  = *(const float4*)(wbase + kk * H + 4);
            *(float4*)(w + 8)  = *(const float4*)(wbase + kk * H + 8);
            *(float4*)(w + 12) = *(const float4*)(wbase + kk * H + 12);
            float av[4];
            #pragma unroll
            for (int r = 0; r < 4; ++r) av[r] = ((const float*)&a[r])[kk];
            #pragma unroll
            for (int r = 0; r < 4; ++r)
                #pragma unroll
                for (int j = 0; j < 16; ++j)
                    acc[r][j] = fmaf(av[r], w[j], acc[r][j]);
        }
    }

    #pragma unroll
    for (int r = 0; r < 4; ++r) {
        int row = row0 + r;
        if (row < n) {
            float sc = scale ? scale[row] : 1.0f;
            float* orow = out + (size_t)row * H + c0;
            #pragma unroll
            for (int j4 = 0; j4 < 4; ++j4) {
                float4 o;
                o.x = acc[r][j4 * 4 + 0] * sc;
                o.y = acc[r][j4 * 4 + 1] * sc;
                o.z = acc[r][j4 * 4 + 2] * sc;
                o.w = acc[r][j4 * 4 + 3] * sc;
                if (bias) {
                    o.x += bias[c0 + j4 * 4 + 0];
                    o.y += bias[c0 + j4 * 4 + 1];
                    o.z += bias[c0 + j4 * 4 + 2];
                    o.w += bias[c0 + j4 * 4 + 3];
                }
                if (relu) {
                    o.x = fmaxf(o.x, 0.f); o.y = fmaxf(o.y, 0.f);
                    o.z = fmaxf(o.z, 0.f); o.w = fmaxf(o.w, 0.f);
                }
                *(float4*)(orow + j4 * 4) = o;
            }
        }
    }
}

// ---------------- vector aggregation: 32 lanes/node, 4 gathers in flight ----------------

__global__ __launch_bounds__(256) void aggregate_k(const float* __restrict__ hs, const int* __restrict__ offs,
                                                   const int* __restrict__ csr, const float* __restrict__ dinv,
                                                   const float* __restrict__ bias, float* __restrict__ hout, int n) {
    int node = blockIdx.x * 8 + (threadIdx.x >> 5);
    int l = threadIdx.x & 31;
    if (node >= n) return;
    const float4* hs4 = (const float4*)hs;
    float4 s0 = hs4[(size_t)node * 32 + l];        // self loop
    float4 s1 = {0, 0, 0, 0}, s2 = {0, 0, 0, 0}, s3 = {0, 0, 0, 0};
    int e0 = offs[node], e1 = offs[node + 1];
    int p = e0;
    for (; p + 4 <= e1; p += 4) {
        int i0 = csr[p], i1 = csr[p + 1], i2 = csr[p + 2], i3 = csr[p + 3];
        float4 v0 = hs4[(size_t)i0 * 32 + l];
        float4 v1 = hs4[(size_t)i1 * 32 + l];
        float4 v2 = hs4[(size_t)i2 * 32 + l];
        float4 v3 = hs4[(size_t)i3 * 32 + l];
        s0.x += v0.x; s0.y += v0.y; s0.z += v0.z; s0.w += v0.w;
        s1.x += v1.x; s1.y += v1.y; s1.z += v1.z; s1.w += v1.w;
        s2.x += v2.x; s2.y += v2.y; s2.z += v2.z; s2.w += v2.w;
        s3.x += v3.x; s3.y += v3.y; s3.z += v3.z; s3.w += v3.w;
    }
    for (; p < e1; ++p) {
        float4 v = hs4[(size_t)csr[p] * 32 + l];
        s0.x += v.x; s0.y += v.y; s0.z += v.z; s0.w += v.w;
    }
    float4 sum;
    sum.x = (s0.x + s1.x) + (s2.x + s3.x);
    sum.y = (s0.y + s1.y) + (s2.y + s3.y);
    sum.z = (s0.z + s1.z) + (s2.z + s3.z);
    sum.w = (s0.w + s1.w) + (s2.w + s3.w);
    float d = dinv[node];
    float4 b = ((const float4*)bias)[l];
    float4 o;
    o.x = fmaxf(fmaf(sum.x, d, b.x), 0.f);
    o.y = fmaxf(fmaf(sum.y, d, b.y), 0.f);
    o.z = fmaxf(fmaf(sum.z, d, b.z), 0.f);
    o.w = fmaxf(fmaf(sum.w, d, b.w), 0.f);
    ((float4*)hout)[(size_t)node * 32 + l] = o;
}

// ---------------- pooling ----------------

__global__ void gstart_k(const int* __restrict__ batch, int* __restrict__ start, int n, int G) {
    int i = blockIdx.x * blockDim.x + threadIdx.x;
    if (i >= n) return;
    int b = batch[i];
    int prev = (i == 0) ? -1 : batch[i - 1];
    for (int g = prev + 1; g <= b; ++g) start[g] = i;
    if (i == n - 1) { for (int g = b + 1; g <= G; ++g) start[g] = n; }
}

__global__ __launch_bounds__(128) void pool_k(const float* __restrict__ h, const int* __restrict__ start,
                                              float* __restrict__ P, int G) {
    int g = blockIdx.x, f = threadIdx.x;
    int s0 = start[g], s1 = start[g + 1];
    float a0 = 0.f, a1 = 0.f, a2 = 0.f, a3 = 0.f;
    int i = s0;
    for (; i + 4 <= s1; i += 4) {
        a0 += h[(size_t)i * H + f];
        a1 += h[(size_t)(i + 1) * H + f];
        a2 += h[(size_t)(i + 2) * H + f];
        a3 += h[(size_t)(i + 3) * H + f];
    }
    for (; i < s1; ++i) a0 += h[(size_t)i * H + f];
    float sum = (a0 + a1) + (a2 + a3);
    float c = (float)(s1 - s0); if (c < 1.f) c = 1.f;
    P[(size_t)g * H + f] = sum / c;
}

// ---------------- final dot ----------------

__global__ __launch_bounds__(256) void outdot_k(const float* __restrict__ g2, const float* __restrict__ Wl3,
                                                const float* __restrict__ bl3, float* __restrict__ out, int G) {
    int gi = blockIdx.x * 4 + (threadIdx.x >> 6);
    int lane = threadIdx.x & 63;
    if (gi >= G) return;
    const float* row = g2 + (size_t)gi * H;
    float v = fmaf(row[lane], Wl3[lane], row[64 + lane] * Wl3[64 + lane]);
    for (int off = 32; off > 0; off >>= 1) v += __shfl_down(v, off);
    if (lane == 0) out[gi] = v + bl3[0];
}

// ---------------- launch ----------------

extern "C" void kernel_launch(void* const* d_in, const int* in_sizes, int n_in,
                              void* d_out, int out_size, void* d_ws, size_t ws_size,
                              hipStream_t stream) {
    const float* x     = (const float*)d_in[0];
    const int*   ei    = (const int*)d_in[1];
    const int*   batch = (const int*)d_in[2];
    const float* W1  = (const float*)d_in[3];  const float* b1  = (const float*)d_in[4];
    const float* W2  = (const float*)d_in[5];  const float* b2  = (const float*)d_in[6];
    const float* W3  = (const float*)d_in[7];  const float* b3  = (const float*)d_in[8];
    const float* Wl1 = (const float*)d_in[9];  const float* bl1 = (const float*)d_in[10];
    const float* Wl2 = (const float*)d_in[11]; const float* bl2 = (const float*)d_in[12];
    const float* Wl3 = (const float*)d_in[13]; const float* bl3 = (const float*)d_in[14];

    const int N = in_sizes[0];
    const int E = in_sizes[1] / 2;
    const int G = out_size;
    const int* srcp = ei;
    const int* dstp = ei + E;
    const int NB = (N + BN - 1) / BN;    // 98 for N=100000 (must be <= MAXNB)

    char* w = (char*)d_ws;
    size_t off = 0;
    auto alloc = [&](size_t bytes) -> void* {
        void* p = w + off;
        off += (bytes + 255) & ~(size_t)255;
        return p;
    };
    int*   coarse = (int*)alloc((size_t)MAXNB * 4);
    int*   cbase  = (int*)alloc((size_t)(MAXNB + 1) * 4);
    int*   gcur   = (int*)alloc((size_t)MAXNB * 4);
    int*   offs   = (int*)alloc((size_t)(N + 1) * 4);
    int*   csr    = (int*)alloc((size_t)E * 4);
    int*   gstart = (int*)alloc((size_t)(G + 1) * 4);
    float* dinv   = (float*)alloc((size_t)N * 4);
    float* sbuf   = (float*)alloc((size_t)N * 4);
    float* tbuf   = (float*)alloc((size_t)N * 4);
    float* A      = (float*)alloc((size_t)N * H * 4);    // h
    float* B      = (float*)alloc((size_t)N * H * 4);    // hs
    float* P      = (float*)alloc((size_t)G * H * 4);
    float* Q      = (float*)alloc((size_t)G * H * 4);
    float* R      = (float*)alloc((size_t)G * H * 4);
    unsigned* pairbuf = (unsigned*)B;   // alias: dead before gemm writes B (stream-ordered)
    (void)ws_size; (void)n_in;

    // --- graph build ---
    hipMemsetAsync(coarse, 0, (size_t)MAXNB * 4, stream);
    hist_coarse_k<<<256, 256, 0, stream>>>(dstp, coarse, E, NB);
    scan_coarse_k<<<1, 1, 0, stream>>>(coarse, cbase, gcur, offs, NB, N, E);
    scatter_pairs_k<<<(E + CHUNK - 1) / CHUNK, 256, 0, stream>>>(srcp, dstp, gcur, pairbuf, E, NB);
    build_csr_k<<<NB, 512, 0, stream>>>(pairbuf, cbase, offs, dinv, csr, N);

    // --- layer 1 (scalar feature) ---
    s_k<<<(N + 255) / 256, 256, 0, stream>>>(x, dinv, sbuf, N);
    agg1_k<<<(N + 255) / 256, 256, 0, stream>>>(sbuf, offs, csr, dinv, tbuf, N);
    expand1_k<<<((size_t)N * 32 + 255) / 256, 256, 0, stream>>>(tbuf, W1, b1, A, N);

    // --- layer 2 ---
    gemm_k<<<(N + 127) / 128, 256, 0, stream>>>(A, W2, nullptr, dinv, B, N, 0);
    aggregate_k<<<(N + 7) / 8, 256, 0, stream>>>(B, offs, csr, dinv, b2, A, N);

    // --- layer 3 ---
    gemm_k<<<(N + 127) / 128, 256, 0, stream>>>(A, W3, nullptr, dinv, B, N, 0);
    aggregate_k<<<(N + 7) / 8, 256, 0, stream>>>(B, offs, csr, dinv, b3, A, N);

    // --- mean pool ---
    gstart_k<<<(N + 255) / 256, 256, 0, stream>>>(batch, gstart, N, G);
    pool_k<<<G, 128, 0, stream>>>(A, gstart, P, G);

    // --- MLP head ---
    gemm_k<<<(G + 127) / 128, 256, 0, stream>>>(P, Wl1, bl1, nullptr, Q, G, 1);
    gemm_k<<<(G + 127) / 128, 256, 0, stream>>>(Q, Wl2, bl2, nullptr, R, G, 1);
    outdot_k<<<(G + 3) / 4, 256, 0, stream>>>(R, Wl3, bl3, (float*)d_out, G);
}

// Round 3
// 584.367 us; speedup vs baseline: 1.3299x; 1.0309x over previous
//
#include <hip/hip_runtime.h>

#define H 128
#define SHIFT 10            // nodes per coarse bucket = 1024
#define BN 1024
#define MAXNB 128           // max coarse buckets (N <= 131072)
#define CHUNK 4096          // edges per scatter block

// ============ graph build: two-level counting sort (no random 4B scatters) ============
// Packing: N=100000 < 2^17, BN=1024 -> record = (local_node<<17)|src fits u32.

__global__ __launch_bounds__(256) void hist_coarse_k(const int* __restrict__ dst,
                                                     int* __restrict__ coarse, int E, int NBv) {
    __shared__ int h[MAXNB];
    int tid = threadIdx.x;
    if (tid < MAXNB) h[tid] = 0;
    __syncthreads();
    for (int e = blockIdx.x * blockDim.x + tid; e < E; e += gridDim.x * blockDim.x)
        atomicAdd(&h[dst[e] >> SHIFT], 1);
    __syncthreads();
    if (tid < NBv && h[tid] > 0) atomicAdd(&coarse[tid], h[tid]);
}

__global__ void scan_coarse_k(const int* __restrict__ coarse, int* __restrict__ cbase,
                              int* __restrict__ gcur, int* __restrict__ offs,
                              int NBv, int N, int E) {
    if (blockIdx.x == 0 && threadIdx.x == 0) {
        int run = 0;
        for (int b = 0; b < NBv; ++b) { int v = coarse[b]; cbase[b] = run; gcur[b] = run; run += v; }
        cbase[NBv] = run;
        offs[N] = E;
    }
}

__global__ __launch_bounds__(256) void scatter_pairs_k(const int* __restrict__ src,
                                                       const int* __restrict__ dst,
                                                       int* __restrict__ gcur,
                                                       unsigned* __restrict__ pairbuf,
                                                       int E, int NBv) {
    __shared__ unsigned stage[CHUNK];
    __shared__ unsigned char stb[CHUNK];
    __shared__ int hist[MAXNB], basel[MAXNB], cur[MAXNB], gbase[MAXNB];
    __shared__ int total;
    int tid = threadIdx.x;
    int base = blockIdx.x * CHUNK;

    int mysrc[16], mydst[16];
    #pragma unroll
    for (int i = 0; i < 16; ++i) {
        int e = base + i * 256 + tid;
        if (e < E) { mysrc[i] = src[e]; mydst[i] = dst[e]; } else mydst[i] = -1;
    }
    if (tid < MAXNB) hist[tid] = 0;
    __syncthreads();
    #pragma unroll
    for (int i = 0; i < 16; ++i)
        if (mydst[i] >= 0) atomicAdd(&hist[mydst[i] >> SHIFT], 1);
    __syncthreads();
    if (tid == 0) {
        int run = 0;
        for (int b = 0; b < NBv; ++b) { basel[b] = run; run += hist[b]; }
        total = run;
    }
    __syncthreads();
    if (tid < NBv) {
        cur[tid] = basel[tid];
        if (hist[tid] > 0) gbase[tid] = atomicAdd(&gcur[tid], hist[tid]);
    }
    __syncthreads();
    #pragma unroll
    for (int i = 0; i < 16; ++i)
        if (mydst[i] >= 0) {
            int b = mydst[i] >> SHIFT;
            int slot = atomicAdd(&cur[b], 1);
            stage[slot] = ((unsigned)(mydst[i] & (BN - 1)) << 17) | (unsigned)mysrc[i];
            stb[slot] = (unsigned char)b;
        }
    __syncthreads();
    for (int s = tid; s < total; s += 256) {
        int b = stb[s];
        pairbuf[gbase[b] + (s - basel[b])] = stage[s];   // contiguous runs -> full-line writes
    }
}

// one block per coarse bucket: LDS histogram + scan -> offs/dinv, then in-bucket scatter (L2-local)
__global__ __launch_bounds__(512) void build_csr_k(const unsigned* __restrict__ pairbuf,
                                                   const int* __restrict__ cbase,
                                                   int* __restrict__ offs, float* __restrict__ dinv,
                                                   int* __restrict__ csr, int N) {
    __shared__ int hist[BN];
    __shared__ int cur[BN];
    __shared__ int ps[512];
    int b = blockIdx.x, tid = threadIdx.x;
    int node0 = b << SHIFT;
    int e0 = cbase[b], e1 = cbase[b + 1];
    hist[tid] = 0; hist[tid + 512] = 0;
    __syncthreads();
    for (int p = e0 + tid; p < e1; p += 512)
        atomicAdd(&hist[pairbuf[p] >> 17], 1);
    __syncthreads();
    int v0 = hist[2 * tid], v1 = hist[2 * tid + 1];
    int pairsum = v0 + v1;
    ps[tid] = pairsum;
    __syncthreads();
    for (int off = 1; off < 512; off <<= 1) {
        int t = (tid >= off) ? ps[tid - off] : 0;
        __syncthreads();
        ps[tid] += t;
        __syncthreads();
    }
    int g0 = e0 + ps[tid] - pairsum;     // exclusive prefix -> global csr offset of node 2*tid
    int n0 = node0 + 2 * tid, n1 = n0 + 1;
    if (n0 < N) { offs[n0] = g0;      dinv[n0] = rsqrtf((float)(v0 + 1)); }
    if (n1 < N) { offs[n1] = g0 + v0; dinv[n1] = rsqrtf((float)(v1 + 1)); }
    cur[2 * tid] = g0; cur[2 * tid + 1] = g0 + v0;
    __syncthreads();
    for (int p = e0 + tid; p < e1; p += 512) {
        unsigned v = pairbuf[p];
        int pos = atomicAdd(&cur[v >> 17], 1);
        csr[pos] = (int)(v & 0x1FFFFu);
    }
}

// ---------------- layer 1 (scalar input feature) ----------------

__global__ void s_k(const float* __restrict__ x, const float* __restrict__ dinv,
                    float* __restrict__ s, int n) {
    int i = blockIdx.x * blockDim.x + threadIdx.x;
    if (i < n) s[i] = x[i] * dinv[i];
}

__global__ void agg1_k(const float* __restrict__ s, const int* __restrict__ offs,
                       const int* __restrict__ csr, const float* __restrict__ dinv,
                       float* __restrict__ t, int n) {
    int i = blockIdx.x * blockDim.x + threadIdx.x;
    if (i >= n) return;
    float sum = s[i];                       // self loop
    int e0 = offs[i], e1 = offs[i + 1];
    float a0 = 0.f, a1 = 0.f, a2 = 0.f, a3 = 0.f;
    int p = e0;
    for (; p + 4 <= e1; p += 4) {
        a0 += s[csr[p]]; a1 += s[csr[p + 1]]; a2 += s[csr[p + 2]]; a3 += s[csr[p + 3]];
    }
    for (; p < e1; ++p) sum += s[csr[p]];
    sum += (a0 + a1) + (a2 + a3);
    t[i] = sum * dinv[i];
}

// ---------------- generic 128-wide GEMM: out = act(in @ W [*scale_row] [+bias]) ----------------

__global__ __launch_bounds__(256) void gemm_k(const float* __restrict__ in, const float* __restrict__ W,
                                              const float* __restrict__ bias, const float* __restrict__ scale,
                                              float* __restrict__ out, int n, int relu) {
    __shared__ float Wl[H * H];
    {
        const float4* Wv = (const float4*)W;
        float4* Wd = (float4*)Wl;
        for (int i = threadIdx.x; i < H * H / 4; i += 256) Wd[i] = Wv[i];
    }
    __syncthreads();
    const int cc = threadIdx.x & 7;
    const int rg = threadIdx.x >> 3;
    const int c0 = cc * 16;
    const int row0 = blockIdx.x * 128 + rg * 4;

    const float* p[4];
    #pragma unroll
    for (int r = 0; r < 4; ++r) {
        int rr = row0 + r; if (rr > n - 1) rr = n - 1;
        p[r] = in + (size_t)rr * H;
    }

    float acc[4][16];
    #pragma unroll
    for (int r = 0; r < 4; ++r)
        #pragma unroll
        for (int j = 0; j < 16; ++j) acc[r][j] = 0.f;

    for (int k4 = 0; k4 < H / 4; ++k4) {
        float4 a[4];
        #pragma unroll
        for (int r = 0; r < 4; ++r) a[r] = *(const float4*)(p[r] + k4 * 4);
        const float* wbase = Wl + (k4 * 4) * H + c0;
        #pragma unroll
        for (int kk = 0; kk < 4; ++kk) {
            float w[16];
            *(float4*)(w + 0)  = *(const float4*)(wbase + kk * H + 0);
            *(float4*)(w + 4)  = *(const float4*)(wbase + kk * H + 4);
            *(float4*)(w + 8)  = *(const float4*)(wbase + kk * H + 8);
            *(float4*)(w + 12) = *(const float4*)(wbase + kk * H + 12);
            float av[4];
            #pragma unroll
            for (int r = 0; r < 4; ++r) av[r] = ((const float*)&a[r])[kk];
            #pragma unroll
            for (int r = 0; r < 4; ++r)
                #pragma unroll
                for (int j = 0; j < 16; ++j)
                    acc[r][j] = fmaf(av[r], w[j], acc[r][j]);
        }
    }

    #pragma unroll
    for (int r = 0; r < 4; ++r) {
        int row = row0 + r;
        if (row < n) {
            float sc = scale ? scale[row] : 1.0f;
            float* orow = out + (size_t)row * H + c0;
            #pragma unroll
            for (int j4 = 0; j4 < 4; ++j4) {
                float4 o;
                o.x = acc[r][j4 * 4 + 0] * sc;
                o.y = acc[r][j4 * 4 + 1] * sc;
                o.z = acc[r][j4 * 4 + 2] * sc;
                o.w = acc[r][j4 * 4 + 3] * sc;
                if (bias) {
                    o.x += bias[c0 + j4 * 4 + 0];
                    o.y += bias[c0 + j4 * 4 + 1];
                    o.z += bias[c0 + j4 * 4 + 2];
                    o.w += bias[c0 + j4 * 4 + 3];
                }
                if (relu) {
                    o.x = fmaxf(o.x, 0.f); o.y = fmaxf(o.y, 0.f);
                    o.z = fmaxf(o.z, 0.f); o.w = fmaxf(o.w, 0.f);
                }
                *(float4*)(orow + j4 * 4) = o;
            }
        }
    }
}

// --------- layer-2 fused GEMM: in-row = relu(t[row]*w1 + b1) computed on the fly ---------

__global__ __launch_bounds__(256) void gemm_rank1_k(const float* __restrict__ t, const float* __restrict__ w1,
                                                    const float* __restrict__ b1, const float* __restrict__ W,
                                                    const float* __restrict__ scale, float* __restrict__ out, int n) {
    __shared__ float Wl[H * H];
    __shared__ float w1l[H], b1l[H];
    {
        const float4* Wv = (const float4*)W;
        float4* Wd = (float4*)Wl;
        for (int i = threadIdx.x; i < H * H / 4; i += 256) Wd[i] = Wv[i];
        if (threadIdx.x < H / 4) {
            ((float4*)w1l)[threadIdx.x] = ((const float4*)w1)[threadIdx.x];
            ((float4*)b1l)[threadIdx.x] = ((const float4*)b1)[threadIdx.x];
        }
    }
    __syncthreads();
    const int cc = threadIdx.x & 7;
    const int rg = threadIdx.x >> 3;
    const int c0 = cc * 16;
    const int row0 = blockIdx.x * 128 + rg * 4;

    float tv[4];
    #pragma unroll
    for (int r = 0; r < 4; ++r) {
        int rr = row0 + r; if (rr > n - 1) rr = n - 1;
        tv[r] = t[rr];
    }

    float acc[4][16];
    #pragma unroll
    for (int r = 0; r < 4; ++r)
        #pragma unroll
        for (int j = 0; j < 16; ++j) acc[r][j] = 0.f;

    for (int k4 = 0; k4 < H / 4; ++k4) {
        float4 wv = *(const float4*)(w1l + k4 * 4);
        float4 bv = *(const float4*)(b1l + k4 * 4);
        float4 a[4];
        #pragma unroll
        for (int r = 0; r < 4; ++r) {
            a[r].x = fmaxf(fmaf(tv[r], wv.x, bv.x), 0.f);
            a[r].y = fmaxf(fmaf(tv[r], wv.y, bv.y), 0.f);
            a[r].z = fmaxf(fmaf(tv[r], wv.z, bv.z), 0.f);
            a[r].w = fmaxf(fmaf(tv[r], wv.w, bv.w), 0.f);
        }
        const float* wbase = Wl + (k4 * 4) * H + c0;
        #pragma unroll
        for (int kk = 0; kk < 4; ++kk) {
            float w[16];
            *(float4*)(w + 0)  = *(const float4*)(wbase + kk * H + 0);
            *(float4*)(w + 4)  = *(const float4*)(wbase + kk * H + 4);
            *(float4*)(w + 8)  = *(const float4*)(wbase + kk * H + 8);
            *(float4*)(w + 12) = *(const float4*)(wbase + kk * H + 12);
            float av[4];
            #pragma unroll
            for (int r = 0; r < 4; ++r) av[r] = ((const float*)&a[r])[kk];
            #pragma unroll
            for (int r = 0; r < 4; ++r)
                #pragma unroll
                for (int j = 0; j < 16; ++j)
                    acc[r][j] = fmaf(av[r], w[j], acc[r][j]);
        }
    }

    #pragma unroll
    for (int r = 0; r < 4; ++r) {
        int row = row0 + r;
        if (row < n) {
            float sc = scale[row];
            float* orow = out + (size_t)row * H + c0;
            #pragma unroll
            for (int j4 = 0; j4 < 4; ++j4) {
                float4 o;
                o.x = acc[r][j4 * 4 + 0] * sc;
                o.y = acc[r][j4 * 4 + 1] * sc;
                o.z = acc[r][j4 * 4 + 2] * sc;
                o.w = acc[r][j4 * 4 + 3] * sc;
                *(float4*)(orow + j4 * 4) = o;
            }
        }
    }
}

// ------- vector aggregation v3: whole wave per node (uniform bounds), 8 KB gathers in flight -------

__global__ __launch_bounds__(256) void aggregate_k(const float* __restrict__ hs, const int* __restrict__ offs,
                                                   const int* __restrict__ csr, const float* __restrict__ dinv,
                                                   const float* __restrict__ bias, float* __restrict__ hout, int n) {
    int node = blockIdx.x * 4 + (threadIdx.x >> 6);
    int lane = threadIdx.x & 63;
    int half = lane >> 5;          // lanes 0-31: even edges, 32-63: odd edges
    int l = lane & 31;
    if (node >= n) return;
    const float4* hs4 = (const float4*)hs;

    float4 acc[8];
    #pragma unroll
    for (int u = 0; u < 8; ++u) acc[u] = make_float4(0.f, 0.f, 0.f, 0.f);
    if (half == 0) acc[0] = hs4[(size_t)node * 32 + l];   // self loop

    int e0 = offs[node], e1 = offs[node + 1];
    int q = e0;
    for (; q + 15 < e1; q += 16) {               // uniform bound: 16 edges, 8 per half
        int idx[8];
        #pragma unroll
        for (int u = 0; u < 8; ++u) idx[u] = csr[q + 2 * u + half];
        #pragma unroll
        for (int u = 0; u < 8; ++u) {
            float4 v = hs4[(size_t)idx[u] * 32 + l];
            acc[u].x += v.x; acc[u].y += v.y; acc[u].z += v.z; acc[u].w += v.w;
        }
    }
    for (; q + 7 < e1; q += 8) {                 // 8 edges, 4 per half
        int idx[4];
        #pragma unroll
        for (int u = 0; u < 4; ++u) idx[u] = csr[q + 2 * u + half];
        #pragma unroll
        for (int u = 0; u < 4; ++u) {
            float4 v = hs4[(size_t)idx[u] * 32 + l];
            acc[u].x += v.x; acc[u].y += v.y; acc[u].z += v.z; acc[u].w += v.w;
        }
    }
    for (; q < e1; q += 2) {                     // last 0-1 edge per half (predicated)
        int off = q + half;
        if (off < e1) {
            float4 v = hs4[(size_t)csr[off] * 32 + l];
            acc[0].x += v.x; acc[0].y += v.y; acc[0].z += v.z; acc[0].w += v.w;
        }
    }

    float4 sum;
    sum.x = ((acc[0].x + acc[1].x) + (acc[2].x + acc[3].x)) + ((acc[4].x + acc[5].x) + (acc[6].x + acc[7].x));
    sum.y = ((acc[0].y + acc[1].y) + (acc[2].y + acc[3].y)) + ((acc[4].y + acc[5].y) + (acc[6].y + acc[7].y));
    sum.z = ((acc[0].z + acc[1].z) + (acc[2].z + acc[3].z)) + ((acc[4].z + acc[5].z) + (acc[6].z + acc[7].z));
    sum.w = ((acc[0].w + acc[1].w) + (acc[2].w + acc[3].w)) + ((acc[4].w + acc[5].w) + (acc[6].w + acc[7].w));

    // cross-half combine
    sum.x += __shfl_xor(sum.x, 32);
    sum.y += __shfl_xor(sum.y, 32);
    sum.z += __shfl_xor(sum.z, 32);
    sum.w += __shfl_xor(sum.w, 32);

    if (half == 0) {
        float d = dinv[node];
        float4 b = ((const float4*)bias)[l];
        float4 o;
        o.x = fmaxf(fmaf(sum.x, d, b.x), 0.f);
        o.y = fmaxf(fmaf(sum.y, d, b.y), 0.f);
        o.z = fmaxf(fmaf(sum.z, d, b.z), 0.f);
        o.w = fmaxf(fmaf(sum.w, d, b.w), 0.f);
        ((float4*)hout)[(size_t)node * 32 + l] = o;
    }
}

// ---------------- pooling (binary search over sorted batch ids) ----------------

__global__ __launch_bounds__(128) void pool_k(const float* __restrict__ h, const int* __restrict__ batch,
                                              float* __restrict__ P, int n, int G) {
    int g = blockIdx.x, f = threadIdx.x;
    int lo = 0, hi = n;
    while (lo < hi) { int m = (lo + hi) >> 1; if (batch[m] < g) lo = m + 1; else hi = m; }
    int s0 = lo;
    hi = n;
    while (lo < hi) { int m = (lo + hi) >> 1; if (batch[m] < g + 1) lo = m + 1; else hi = m; }
    int s1 = lo;
    float a0 = 0.f, a1 = 0.f, a2 = 0.f, a3 = 0.f;
    int i = s0;
    for (; i + 4 <= s1; i += 4) {
        a0 += h[(size_t)i * H + f];
        a1 += h[(size_t)(i + 1) * H + f];
        a2 += h[(size_t)(i + 2) * H + f];
        a3 += h[(size_t)(i + 3) * H + f];
    }
    for (; i < s1; ++i) a0 += h[(size_t)i * H + f];
    float sum = (a0 + a1) + (a2 + a3);
    float c = (float)(s1 - s0); if (c < 1.f) c = 1.f;
    P[(size_t)g * H + f] = sum / c;
}

// ---------------- final dot ----------------

__global__ __launch_bounds__(256) void outdot_k(const float* __restrict__ g2, const float* __restrict__ Wl3,
                                                const float* __restrict__ bl3, float* __restrict__ out, int G) {
    int gi = blockIdx.x * 4 + (threadIdx.x >> 6);
    int lane = threadIdx.x & 63;
    if (gi >= G) return;
    const float* row = g2 + (size_t)gi * H;
    float v = fmaf(row[lane], Wl3[lane], row[64 + lane] * Wl3[64 + lane]);
    for (int off = 32; off > 0; off >>= 1) v += __shfl_down(v, off);
    if (lane == 0) out[gi] = v + bl3[0];
}

// ---------------- launch ----------------

extern "C" void kernel_launch(void* const* d_in, const int* in_sizes, int n_in,
                              void* d_out, int out_size, void* d_ws, size_t ws_size,
                              hipStream_t stream) {
    const float* x     = (const float*)d_in[0];
    const int*   ei    = (const int*)d_in[1];
    const int*   batch = (const int*)d_in[2];
    const float* W1  = (const float*)d_in[3];  const float* b1  = (const float*)d_in[4];
    const float* W2  = (const float*)d_in[5];  const float* b2  = (const float*)d_in[6];
    const float* W3  = (const float*)d_in[7];  const float* b3  = (const float*)d_in[8];
    const float* Wl1 = (const float*)d_in[9];  const float* bl1 = (const float*)d_in[10];
    const float* Wl2 = (const float*)d_in[11]; const float* bl2 = (const float*)d_in[12];
    const float* Wl3 = (const float*)d_in[13]; const float* bl3 = (const float*)d_in[14];

    const int N = in_sizes[0];
    const int E = in_sizes[1] / 2;
    const int G = out_size;
    const int* srcp = ei;
    const int* dstp = ei + E;
    const int NB = (N + BN - 1) / BN;    // 98 for N=100000 (must be <= MAXNB)

    char* w = (char*)d_ws;
    size_t off = 0;
    auto alloc = [&](size_t bytes) -> void* {
        void* p = w + off;
        off += (bytes + 255) & ~(size_t)255;
        return p;
    };
    int*   coarse = (int*)alloc((size_t)MAXNB * 4);
    int*   cbase  = (int*)alloc((size_t)(MAXNB + 1) * 4);
    int*   gcur   = (int*)alloc((size_t)MAXNB * 4);
    int*   offs   = (int*)alloc((size_t)(N + 1) * 4);
    int*   csr    = (int*)alloc((size_t)E * 4);
    float* dinv   = (float*)alloc((size_t)N * 4);
    float* sbuf   = (float*)alloc((size_t)N * 4);
    float* tbuf   = (float*)alloc((size_t)N * 4);
    float* A      = (float*)alloc((size_t)N * H * 4);    // h
    float* B      = (float*)alloc((size_t)N * H * 4);    // hs
    float* P      = (float*)alloc((size_t)G * H * 4);
    float* Q      = (float*)alloc((size_t)G * H * 4);
    float* R      = (float*)alloc((size_t)G * H * 4);
    unsigned* pairbuf = (unsigned*)B;   // alias: dead before gemm_rank1 writes B (stream-ordered)
    (void)ws_size; (void)n_in;

    // --- graph build ---
    hipMemsetAsync(coarse, 0, (size_t)MAXNB * 4, stream);
    hist_coarse_k<<<256, 256, 0, stream>>>(dstp, coarse, E, NB);
    scan_coarse_k<<<1, 1, 0, stream>>>(coarse, cbase, gcur, offs, NB, N, E);
    scatter_pairs_k<<<(E + CHUNK - 1) / CHUNK, 256, 0, stream>>>(srcp, dstp, gcur, pairbuf, E, NB);
    build_csr_k<<<NB, 512, 0, stream>>>(pairbuf, cbase, offs, dinv, csr, N);

    // --- layer 1 (scalar feature) ---
    s_k<<<(N + 255) / 256, 256, 0, stream>>>(x, dinv, sbuf, N);
    agg1_k<<<(N + 255) / 256, 256, 0, stream>>>(sbuf, offs, csr, dinv, tbuf, N);

    // --- layer 2 (fused rank-1 expand + GEMM) ---
    gemm_rank1_k<<<(N + 127) / 128, 256, 0, stream>>>(tbuf, W1, b1, W2, dinv, B, N);
    aggregate_k<<<(N + 3) / 4, 256, 0, stream>>>(B, offs, csr, dinv, b2, A, N);

    // --- layer 3 ---
    gemm_k<<<(N + 127) / 128, 256, 0, stream>>>(A, W3, nullptr, dinv, B, N, 0);
    aggregate_k<<<(N + 3) / 4, 256, 0, stream>>>(B, offs, csr, dinv, b3, A, N);

    // --- mean pool ---
    pool_k<<<G, 128, 0, stream>>>(A, batch, P, N, G);

    // --- MLP head ---
    gemm_k<<<(G + 127) / 128, 256, 0, stream>>>(P, Wl1, bl1, nullptr, Q, G, 1);
    gemm_k<<<(G + 127) / 128, 256, 0, stream>>>(Q, Wl2, bl2, nullptr, R, G, 1);
    outdot_k<<<(G + 3) / 4, 256, 0, stream>>>(R, Wl3, bl3, (float*)d_out, G);
}

// Round 4
// 577.940 us; speedup vs baseline: 1.3447x; 1.0111x over previous
//
#include <hip/hip_runtime.h>

#define H 128
#define SHIFT 10            // nodes per coarse bucket = 1024
#define BN 1024
#define MAXNB 128           // max coarse buckets (N <= 131072)
#define CHUNK 4096          // edges per scatter block

// ============ graph build: two-level counting sort (no random 4B scatters) ============

__global__ __launch_bounds__(256) void hist_coarse_k(const int* __restrict__ dst,
                                                     int* __restrict__ coarse, int E, int NBv) {
    __shared__ int h[MAXNB];
    int tid = threadIdx.x;
    if (tid < MAXNB) h[tid] = 0;
    __syncthreads();
    for (int e = blockIdx.x * blockDim.x + tid; e < E; e += gridDim.x * blockDim.x)
        atomicAdd(&h[dst[e] >> SHIFT], 1);
    __syncthreads();
    if (tid < NBv && h[tid] > 0) atomicAdd(&coarse[tid], h[tid]);
}

__global__ void scan_coarse_k(const int* __restrict__ coarse, int* __restrict__ cbase,
                              int* __restrict__ gcur, int* __restrict__ offs,
                              int NBv, int N, int E) {
    if (blockIdx.x == 0 && threadIdx.x == 0) {
        int run = 0;
        for (int b = 0; b < NBv; ++b) { int v = coarse[b]; cbase[b] = run; gcur[b] = run; run += v; }
        cbase[NBv] = run;
        offs[N] = E;
    }
}

__global__ __launch_bounds__(256) void scatter_pairs_k(const int* __restrict__ src,
                                                       const int* __restrict__ dst,
                                                       int* __restrict__ gcur,
                                                       unsigned* __restrict__ pairbuf,
                                                       int E, int NBv) {
    __shared__ unsigned stage[CHUNK];
    __shared__ unsigned char stb[CHUNK];
    __shared__ int hist[MAXNB], basel[MAXNB], cur[MAXNB], gbase[MAXNB];
    __shared__ int total;
    int tid = threadIdx.x;
    int base = blockIdx.x * CHUNK;

    int mysrc[16], mydst[16];
    #pragma unroll
    for (int i = 0; i < 16; ++i) {
        int e = base + i * 256 + tid;
        if (e < E) { mysrc[i] = src[e]; mydst[i] = dst[e]; } else mydst[i] = -1;
    }
    if (tid < MAXNB) hist[tid] = 0;
    __syncthreads();
    #pragma unroll
    for (int i = 0; i < 16; ++i)
        if (mydst[i] >= 0) atomicAdd(&hist[mydst[i] >> SHIFT], 1);
    __syncthreads();
    if (tid == 0) {
        int run = 0;
        for (int b = 0; b < NBv; ++b) { basel[b] = run; run += hist[b]; }
        total = run;
    }
    __syncthreads();
    if (tid < NBv) {
        cur[tid] = basel[tid];
        if (hist[tid] > 0) gbase[tid] = atomicAdd(&gcur[tid], hist[tid]);
    }
    __syncthreads();
    #pragma unroll
    for (int i = 0; i < 16; ++i)
        if (mydst[i] >= 0) {
            int b = mydst[i] >> SHIFT;
            int slot = atomicAdd(&cur[b], 1);
            stage[slot] = ((unsigned)(mydst[i] & (BN - 1)) << 17) | (unsigned)mysrc[i];
            stb[slot] = (unsigned char)b;
        }
    __syncthreads();
    for (int s = tid; s < total; s += 256) {
        int b = stb[s];
        pairbuf[gbase[b] + (s - basel[b])] = stage[s];
    }
}

__global__ __launch_bounds__(512) void build_csr_k(const unsigned* __restrict__ pairbuf,
                                                   const int* __restrict__ cbase,
                                                   int* __restrict__ offs, float* __restrict__ dinv,
                                                   int* __restrict__ csr, int N) {
    __shared__ int hist[BN];
    __shared__ int cur[BN];
    __shared__ int ps[512];
    int b = blockIdx.x, tid = threadIdx.x;
    int node0 = b << SHIFT;
    int e0 = cbase[b], e1 = cbase[b + 1];
    hist[tid] = 0; hist[tid + 512] = 0;
    __syncthreads();
    for (int p = e0 + tid; p < e1; p += 512)
        atomicAdd(&hist[pairbuf[p] >> 17], 1);
    __syncthreads();
    int v0 = hist[2 * tid], v1 = hist[2 * tid + 1];
    int pairsum = v0 + v1;
    ps[tid] = pairsum;
    __syncthreads();
    for (int off = 1; off < 512; off <<= 1) {
        int t = (tid >= off) ? ps[tid - off] : 0;
        __syncthreads();
        ps[tid] += t;
        __syncthreads();
    }
    int g0 = e0 + ps[tid] - pairsum;
    int n0 = node0 + 2 * tid, n1 = n0 + 1;
    if (n0 < N) { offs[n0] = g0;      dinv[n0] = rsqrtf((float)(v0 + 1)); }
    if (n1 < N) { offs[n1] = g0 + v0; dinv[n1] = rsqrtf((float)(v1 + 1)); }
    cur[2 * tid] = g0; cur[2 * tid + 1] = g0 + v0;
    __syncthreads();
    for (int p = e0 + tid; p < e1; p += 512) {
        unsigned v = pairbuf[p];
        int pos = atomicAdd(&cur[v >> 17], 1);
        csr[pos] = (int)(v & 0x1FFFFu);
    }
}

// ---------------- layer 1 (scalar input feature) ----------------

__global__ void s_k(const float* __restrict__ x, const float* __restrict__ dinv,
                    float* __restrict__ s, int n) {
    int i = blockIdx.x * blockDim.x + threadIdx.x;
    if (i < n) s[i] = x[i] * dinv[i];
}

__global__ void agg1_k(const float* __restrict__ s, const int* __restrict__ offs,
                       const int* __restrict__ csr, const float* __restrict__ dinv,
                       float* __restrict__ t, int n) {
    int i = blockIdx.x * blockDim.x + threadIdx.x;
    if (i >= n) return;
    float sum = s[i];
    int e0 = offs[i], e1 = offs[i + 1];
    float a0 = 0.f, a1 = 0.f, a2 = 0.f, a3 = 0.f;
    int p = e0;
    for (; p + 4 <= e1; p += 4) {
        a0 += s[csr[p]]; a1 += s[csr[p + 1]]; a2 += s[csr[p + 2]]; a3 += s[csr[p + 3]];
    }
    for (; p < e1; ++p) sum += s[csr[p]];
    sum += (a0 + a1) + (a2 + a3);
    t[i] = sum * dinv[i];
}

// ---------------- generic 128-wide GEMM ----------------

__global__ __launch_bounds__(256) void gemm_k(const float* __restrict__ in, const float* __restrict__ W,
                                              const float* __restrict__ bias, const float* __restrict__ scale,
                                              float* __restrict__ out, int n, int relu) {
    __shared__ float Wl[H * H];
    {
        const float4* Wv = (const float4*)W;
        float4* Wd = (float4*)Wl;
        for (int i = threadIdx.x; i < H * H / 4; i += 256) Wd[i] = Wv[i];
    }
    __syncthreads();
    const int cc = threadIdx.x & 7;
    const int rg = threadIdx.x >> 3;
    const int c0 = cc * 16;
    const int row0 = blockIdx.x * 128 + rg * 4;

    const float* p[4];
    #pragma unroll
    for (int r = 0; r < 4; ++r) {
        int rr = row0 + r; if (rr > n - 1) rr = n - 1;
        p[r] = in + (size_t)rr * H;
    }

    float acc[4][16];
    #pragma unroll
    for (int r = 0; r < 4; ++r)
        #pragma unroll
        for (int j = 0; j < 16; ++j) acc[r][j] = 0.f;

    for (int k4 = 0; k4 < H / 4; ++k4) {
        float4 a[4];
        #pragma unroll
        for (int r = 0; r < 4; ++r) a[r] = *(const float4*)(p[r] + k4 * 4);
        const float* wbase = Wl + (k4 * 4) * H + c0;
        #pragma unroll
        for (int kk = 0; kk < 4; ++kk) {
            float w[16];
            *(float4*)(w + 0)  = *(const float4*)(wbase + kk * H + 0);
            *(float4*)(w + 4)  = *(const float4*)(wbase + kk * H + 4);
            *(float4*)(w + 8)  = *(const float4*)(wbase + kk * H + 8);
            *(float4*)(w + 12) = *(const float4*)(wbase + kk * H + 12);
            float av[4];
            #pragma unroll
            for (int r = 0; r < 4; ++r) av[r] = ((const float*)&a[r])[kk];
            #pragma unroll
            for (int r = 0; r < 4; ++r)
                #pragma unroll
                for (int j = 0; j < 16; ++j)
                    acc[r][j] = fmaf(av[r], w[j], acc[r][j]);
        }
    }

    #pragma unroll
    for (int r = 0; r < 4; ++r) {
        int row = row0 + r;
        if (row < n) {
            float sc = scale ? scale[row] : 1.0f;
            float* orow = out + (size_t)row * H + c0;
            #pragma unroll
            for (int j4 = 0; j4 < 4; ++j4) {
                float4 o;
                o.x = acc[r][j4 * 4 + 0] * sc;
                o.y = acc[r][j4 * 4 + 1] * sc;
                o.z = acc[r][j4 * 4 + 2] * sc;
                o.w = acc[r][j4 * 4 + 3] * sc;
                if (bias) {
                    o.x += bias[c0 + j4 * 4 + 0];
                    o.y += bias[c0 + j4 * 4 + 1];
                    o.z += bias[c0 + j4 * 4 + 2];
                    o.w += bias[c0 + j4 * 4 + 3];
                }
                if (relu) {
                    o.x = fmaxf(o.x, 0.f); o.y = fmaxf(o.y, 0.f);
                    o.z = fmaxf(o.z, 0.f); o.w = fmaxf(o.w, 0.f);
                }
                *(float4*)(orow + j4 * 4) = o;
            }
        }
    }
}

// --------- layer-2 fused GEMM: in-row = relu(t[row]*w1 + b1) on the fly ---------

__global__ __launch_bounds__(256) void gemm_rank1_k(const float* __restrict__ t, const float* __restrict__ w1,
                                                    const float* __restrict__ b1, const float* __restrict__ W,
                                                    const float* __restrict__ scale, float* __restrict__ out, int n) {
    __shared__ float Wl[H * H];
    __shared__ float w1l[H], b1l[H];
    {
        const float4* Wv = (const float4*)W;
        float4* Wd = (float4*)Wl;
        for (int i = threadIdx.x; i < H * H / 4; i += 256) Wd[i] = Wv[i];
        if (threadIdx.x < H / 4) {
            ((float4*)w1l)[threadIdx.x] = ((const float4*)w1)[threadIdx.x];
            ((float4*)b1l)[threadIdx.x] = ((const float4*)b1)[threadIdx.x];
        }
    }
    __syncthreads();
    const int cc = threadIdx.x & 7;
    const int rg = threadIdx.x >> 3;
    const int c0 = cc * 16;
    const int row0 = blockIdx.x * 128 + rg * 4;

    float tv[4];
    #pragma unroll
    for (int r = 0; r < 4; ++r) {
        int rr = row0 + r; if (rr > n - 1) rr = n - 1;
        tv[r] = t[rr];
    }

    float acc[4][16];
    #pragma unroll
    for (int r = 0; r < 4; ++r)
        #pragma unroll
        for (int j = 0; j < 16; ++j) acc[r][j] = 0.f;

    for (int k4 = 0; k4 < H / 4; ++k4) {
        float4 wv = *(const float4*)(w1l + k4 * 4);
        float4 bv = *(const float4*)(b1l + k4 * 4);
        float4 a[4];
        #pragma unroll
        for (int r = 0; r < 4; ++r) {
            a[r].x = fmaxf(fmaf(tv[r], wv.x, bv.x), 0.f);
            a[r].y = fmaxf(fmaf(tv[r], wv.y, bv.y), 0.f);
            a[r].z = fmaxf(fmaf(tv[r], wv.z, bv.z), 0.f);
            a[r].w = fmaxf(fmaf(tv[r], wv.w, bv.w), 0.f);
        }
        const float* wbase = Wl + (k4 * 4) * H + c0;
        #pragma unroll
        for (int kk = 0; kk < 4; ++kk) {
            float w[16];
            *(float4*)(w + 0)  = *(const float4*)(wbase + kk * H + 0);
            *(float4*)(w + 4)  = *(const float4*)(wbase + kk * H + 4);
            *(float4*)(w + 8)  = *(const float4*)(wbase + kk * H + 8);
            *(float4*)(w + 12) = *(const float4*)(wbase + kk * H + 12);
            float av[4];
            #pragma unroll
            for (int r = 0; r < 4; ++r) av[r] = ((const float*)&a[r])[kk];
            #pragma unroll
            for (int r = 0; r < 4; ++r)
                #pragma unroll
                for (int j = 0; j < 16; ++j)
                    acc[r][j] = fmaf(av[r], w[j], acc[r][j]);
        }
    }

    #pragma unroll
    for (int r = 0; r < 4; ++r) {
        int row = row0 + r;
        if (row < n) {
            float sc = scale[row];
            float* orow = out + (size_t)row * H + c0;
            #pragma unroll
            for (int j4 = 0; j4 < 4; ++j4) {
                float4 o;
                o.x = acc[r][j4 * 4 + 0] * sc;
                o.y = acc[r][j4 * 4 + 1] * sc;
                o.z = acc[r][j4 * 4 + 2] * sc;
                o.w = acc[r][j4 * 4 + 3] * sc;
                *(float4*)(orow + j4 * 4) = o;
            }
        }
    }
}

// ------- whole-wave gather of one node's neighbor-row sum (v3 pattern) -------
// returns per-lane float4; valid on lanes 0-31 after cross-half combine

__device__ __forceinline__ float4 gather_row_sum(const float4* __restrict__ hs4,
                                                 const int* __restrict__ csr,
                                                 int node, int e0, int e1, int half, int l) {
    float4 acc[8];
    #pragma unroll
    for (int u = 0; u < 8; ++u) acc[u] = make_float4(0.f, 0.f, 0.f, 0.f);
    if (half == 0) acc[0] = hs4[(size_t)node * 32 + l];   // self loop
    int q = e0;
    for (; q + 15 < e1; q += 16) {
        int idx[8];
        #pragma unroll
        for (int u = 0; u < 8; ++u) idx[u] = csr[q + 2 * u + half];
        #pragma unroll
        for (int u = 0; u < 8; ++u) {
            float4 v = hs4[(size_t)idx[u] * 32 + l];
            acc[u].x += v.x; acc[u].y += v.y; acc[u].z += v.z; acc[u].w += v.w;
        }
    }
    for (; q + 7 < e1; q += 8) {
        int idx[4];
        #pragma unroll
        for (int u = 0; u < 4; ++u) idx[u] = csr[q + 2 * u + half];
        #pragma unroll
        for (int u = 0; u < 4; ++u) {
            float4 v = hs4[(size_t)idx[u] * 32 + l];
            acc[u].x += v.x; acc[u].y += v.y; acc[u].z += v.z; acc[u].w += v.w;
        }
    }
    for (; q < e1; q += 2) {
        int off = q + half;
        if (off < e1) {
            float4 v = hs4[(size_t)csr[off] * 32 + l];
            acc[0].x += v.x; acc[0].y += v.y; acc[0].z += v.z; acc[0].w += v.w;
        }
    }
    float4 sum;
    sum.x = ((acc[0].x + acc[1].x) + (acc[2].x + acc[3].x)) + ((acc[4].x + acc[5].x) + (acc[6].x + acc[7].x));
    sum.y = ((acc[0].y + acc[1].y) + (acc[2].y + acc[3].y)) + ((acc[4].y + acc[5].y) + (acc[6].y + acc[7].y));
    sum.z = ((acc[0].z + acc[1].z) + (acc[2].z + acc[3].z)) + ((acc[4].z + acc[5].z) + (acc[6].z + acc[7].z));
    sum.w = ((acc[0].w + acc[1].w) + (acc[2].w + acc[3].w)) + ((acc[4].w + acc[5].w) + (acc[6].w + acc[7].w));
    sum.x += __shfl_xor(sum.x, 32);
    sum.y += __shfl_xor(sum.y, 32);
    sum.z += __shfl_xor(sum.z, 32);
    sum.w += __shfl_xor(sum.w, 32);
    return sum;
}

// ------- layer-2 aggregation: one node per wave -------

__global__ __launch_bounds__(256) void aggregate_k(const float* __restrict__ hs, const int* __restrict__ offs,
                                                   const int* __restrict__ csr, const float* __restrict__ dinv,
                                                   const float* __restrict__ bias, float* __restrict__ hout, int n) {
    int node = blockIdx.x * 4 + (threadIdx.x >> 6);
    int lane = threadIdx.x & 63;
    int half = lane >> 5;
    int l = lane & 31;
    if (node >= n) return;
    const float4* hs4 = (const float4*)hs;
    float4 sum = gather_row_sum(hs4, csr, node, offs[node], offs[node + 1], half, l);
    if (half == 0) {
        float d = dinv[node];
        float4 b = ((const float4*)bias)[l];
        float4 o;
        o.x = fmaxf(fmaf(sum.x, d, b.x), 0.f);
        o.y = fmaxf(fmaf(sum.y, d, b.y), 0.f);
        o.z = fmaxf(fmaf(sum.z, d, b.z), 0.f);
        o.w = fmaxf(fmaf(sum.w, d, b.w), 0.f);
        ((float4*)hout)[(size_t)node * 32 + l] = o;
    }
}

// ------- layer-3 aggregation fused with mean-pool accumulation -------
// wave owns 32 consecutive nodes; pooled partial kept in registers, flushed on graph change.

__global__ __launch_bounds__(256) void agg_pool_k(const float* __restrict__ hs, const int* __restrict__ offs,
                                                  const int* __restrict__ csr, const float* __restrict__ dinv,
                                                  const float* __restrict__ bias, const int* __restrict__ batch,
                                                  float* __restrict__ P, int n) {
    int wave = threadIdx.x >> 6;
    int lane = threadIdx.x & 63;
    int half = lane >> 5;
    int l = lane & 31;
    int nodeBase = blockIdx.x * 128 + wave * 32;
    if (nodeBase >= n) return;
    const float4* hs4 = (const float4*)hs;
    float4 b = ((const float4*)bias)[l & 31];

    float4 pacc = make_float4(0.f, 0.f, 0.f, 0.f);
    int cur_g = -1;
    for (int i = 0; i < 32; ++i) {
        int node = nodeBase + i;
        if (node >= n) break;
        float4 sum = gather_row_sum(hs4, csr, node, offs[node], offs[node + 1], half, l);
        if (half == 0) {
            float d = dinv[node];
            float4 o;
            o.x = fmaxf(fmaf(sum.x, d, b.x), 0.f);
            o.y = fmaxf(fmaf(sum.y, d, b.y), 0.f);
            o.z = fmaxf(fmaf(sum.z, d, b.z), 0.f);
            o.w = fmaxf(fmaf(sum.w, d, b.w), 0.f);
            int g = batch[node];
            if (g != cur_g) {
                if (cur_g >= 0) {
                    float* pg = P + (size_t)cur_g * H + l * 4;
                    atomicAdd(pg + 0, pacc.x); atomicAdd(pg + 1, pacc.y);
                    atomicAdd(pg + 2, pacc.z); atomicAdd(pg + 3, pacc.w);
                }
                cur_g = g; pacc = o;
            } else {
                pacc.x += o.x; pacc.y += o.y; pacc.z += o.z; pacc.w += o.w;
            }
        }
    }
    if (half == 0 && cur_g >= 0) {
        float* pg = P + (size_t)cur_g * H + l * 4;
        atomicAdd(pg + 0, pacc.x); atomicAdd(pg + 1, pacc.y);
        atomicAdd(pg + 2, pacc.z); atomicAdd(pg + 3, pacc.w);
    }
}

// ------- fused MLP head: mean + relu(@Wl1+bl1) + relu(@Wl2+bl2) + dot Wl3 + bl3 -------
// one block per 128 graphs (G=2048 -> 16 blocks)

__global__ __launch_bounds__(256) void head_k(const float* __restrict__ P, const int* __restrict__ batch,
                                              const float* __restrict__ Wl1, const float* __restrict__ bl1,
                                              const float* __restrict__ Wl2, const float* __restrict__ bl2,
                                              const float* __restrict__ Wl3, const float* __restrict__ bl3,
                                              float* __restrict__ out, int n, int G) {
    __shared__ float Wb[H * H];
    __shared__ float Tl[H * 133];
    __shared__ float invc[H];
    __shared__ float w3l[H];
    int tid = threadIdx.x;
    int g0 = blockIdx.x * 128;

    if (tid < 128) {
        int g = g0 + tid;
        int lo = 0, hi = n;
        while (lo < hi) { int m = (lo + hi) >> 1; if (batch[m] < g) lo = m + 1; else hi = m; }
        int a0 = lo; hi = n;
        while (lo < hi) { int m = (lo + hi) >> 1; if (batch[m] < g + 1) lo = m + 1; else hi = m; }
        int c = lo - a0;
        invc[tid] = 1.0f / (float)(c > 1 ? c : 1);
        w3l[tid] = Wl3[tid];
    }
    for (int i = tid; i < H * H / 4; i += 256) ((float4*)Wb)[i] = ((const float4*)Wl1)[i];
    __syncthreads();

    const int cc = tid & 7, rg = tid >> 3, c0 = cc * 16;
    float acc[4][16];

    // phase 1: g1 = relu(mean @ Wl1 + bl1) -> Tl
    #pragma unroll
    for (int r = 0; r < 4; ++r)
        #pragma unroll
        for (int j = 0; j < 16; ++j) acc[r][j] = 0.f;
    const float4* P4 = (const float4*)P;
    float iv[4];
    #pragma unroll
    for (int r = 0; r < 4; ++r) iv[r] = invc[rg * 4 + r];
    for (int k4 = 0; k4 < H / 4; ++k4) {
        float4 a[4];
        #pragma unroll
        for (int r = 0; r < 4; ++r) {
            float4 v = P4[(size_t)(g0 + rg * 4 + r) * 32 + k4];
            a[r].x = v.x * iv[r]; a[r].y = v.y * iv[r]; a[r].z = v.z * iv[r]; a[r].w = v.w * iv[r];
        }
        const float* wbase = Wb + (k4 * 4) * H + c0;
        #pragma unroll
        for (int kk = 0; kk < 4; ++kk) {
            float w[16];
            *(float4*)(w + 0)  = *(const float4*)(wbase + kk * H + 0);
            *(float4*)(w + 4)  = *(const float4*)(wbase + kk * H + 4);
            *(float4*)(w + 8)  = *(const float4*)(wbase + kk * H + 8);
            *(float4*)(w + 12) = *(const float4*)(wbase + kk * H + 12);
            float av[4];
            #pragma unroll
            for (int r = 0; r < 4; ++r) av[r] = ((const float*)&a[r])[kk];
            #pragma unroll
            for (int r = 0; r < 4; ++r)
                #pragma unroll
                for (int j = 0; j < 16; ++j)
                    acc[r][j] = fmaf(av[r], w[j], acc[r][j]);
        }
    }
    #pragma unroll
    for (int r = 0; r < 4; ++r) {
        int rl = rg * 4 + r;
        #pragma unroll
        for (int j = 0; j < 16; ++j)
            Tl[rl * 133 + c0 + j] = fmaxf(acc[r][j] + bl1[c0 + j], 0.f);
    }
    __syncthreads();
    for (int i = tid; i < H * H / 4; i += 256) ((float4*)Wb)[i] = ((const float4*)Wl2)[i];
    __syncthreads();

    // phase 2: g2 = relu(g1 @ Wl2 + bl2); dot with Wl3
    #pragma unroll
    for (int r = 0; r < 4; ++r)
        #pragma unroll
        for (int j = 0; j < 16; ++j) acc[r][j] = 0.f;
    for (int k4 = 0; k4 < H / 4; ++k4) {
        float4 a[4];
        #pragma unroll
        for (int r = 0; r < 4; ++r) a[r] = *(const float4*)(Tl + (rg * 4 + r) * 133 + k4 * 4);
        const float* wbase = Wb + (k4 * 4) * H + c0;
        #pragma unroll
        for (int kk = 0; kk < 4; ++kk) {
            float w[16];
            *(float4*)(w + 0)  = *(const float4*)(wbase + kk * H + 0);
            *(float4*)(w + 4)  = *(const float4*)(wbase + kk * H + 4);
            *(float4*)(w + 8)  = *(const float4*)(wbase + kk * H + 8);
            *(float4*)(w + 12) = *(const float4*)(wbase + kk * H + 12);
            float av[4];
            #pragma unroll
            for (int r = 0; r < 4; ++r) av[r] = ((const float*)&a[r])[kk];
            #pragma unroll
            for (int r = 0; r < 4; ++r)
                #pragma unroll
                for (int j = 0; j < 16; ++j)
                    acc[r][j] = fmaf(av[r], w[j], acc[r][j]);
        }
    }
    float part[4];
    #pragma unroll
    for (int r = 0; r < 4; ++r) {
        float s = 0.f;
        #pragma unroll
        for (int j = 0; j < 16; ++j)
            s += fmaxf(acc[r][j] + bl2[c0 + j], 0.f) * w3l[c0 + j];
        part[r] = s;
    }
    #pragma unroll
    for (int off = 1; off < 8; off <<= 1)
        #pragma unroll
        for (int r = 0; r < 4; ++r) part[r] += __shfl_xor(part[r], off);
    if (cc == 0) {
        float bb = bl3[0];
        #pragma unroll
        for (int r = 0; r < 4; ++r) out[g0 + rg * 4 + r] = part[r] + bb;
    }
}

// ---------------- launch ----------------

extern "C" void kernel_launch(void* const* d_in, const int* in_sizes, int n_in,
                              void* d_out, int out_size, void* d_ws, size_t ws_size,
                              hipStream_t stream) {
    const float* x     = (const float*)d_in[0];
    const int*   ei    = (const int*)d_in[1];
    const int*   batch = (const int*)d_in[2];
    const float* W1  = (const float*)d_in[3];  const float* b1  = (const float*)d_in[4];
    const float* W2  = (const float*)d_in[5];  const float* b2  = (const float*)d_in[6];
    const float* W3  = (const float*)d_in[7];  const float* b3  = (const float*)d_in[8];
    const float* Wl1 = (const float*)d_in[9];  const float* bl1 = (const float*)d_in[10];
    const float* Wl2 = (const float*)d_in[11]; const float* bl2 = (const float*)d_in[12];
    const float* Wl3 = (const float*)d_in[13]; const float* bl3 = (const float*)d_in[14];

    const int N = in_sizes[0];
    const int E = in_sizes[1] / 2;
    const int G = out_size;
    const int* srcp = ei;
    const int* dstp = ei + E;
    const int NB = (N + BN - 1) / BN;

    char* w = (char*)d_ws;
    size_t off = 0;
    auto alloc = [&](size_t bytes) -> void* {
        void* p = w + off;
        off += (bytes + 255) & ~(size_t)255;
        return p;
    };
    int*   coarse = (int*)alloc((size_t)MAXNB * 4);
    int*   cbase  = (int*)alloc((size_t)(MAXNB + 1) * 4);
    int*   gcur   = (int*)alloc((size_t)MAXNB * 4);
    int*   offs   = (int*)alloc((size_t)(N + 1) * 4);
    int*   csr    = (int*)alloc((size_t)E * 4);
    float* dinv   = (float*)alloc((size_t)N * 4);
    float* sbuf   = (float*)alloc((size_t)N * 4);
    float* tbuf   = (float*)alloc((size_t)N * 4);
    float* A      = (float*)alloc((size_t)N * H * 4);    // h
    float* B      = (float*)alloc((size_t)N * H * 4);    // hs
    float* P      = (float*)alloc((size_t)G * H * 4);    // pooled sums
    unsigned* pairbuf = (unsigned*)B;   // alias: dead before gemm_rank1 writes B
    (void)ws_size; (void)n_in;

    // --- graph build ---
    hipMemsetAsync(coarse, 0, (size_t)MAXNB * 4, stream);
    hipMemsetAsync(P, 0, (size_t)G * H * 4, stream);
    hist_coarse_k<<<256, 256, 0, stream>>>(dstp, coarse, E, NB);
    scan_coarse_k<<<1, 1, 0, stream>>>(coarse, cbase, gcur, offs, NB, N, E);
    scatter_pairs_k<<<(E + CHUNK - 1) / CHUNK, 256, 0, stream>>>(srcp, dstp, gcur, pairbuf, E, NB);
    build_csr_k<<<NB, 512, 0, stream>>>(pairbuf, cbase, offs, dinv, csr, N);

    // --- layer 1 (scalar feature) ---
    s_k<<<(N + 255) / 256, 256, 0, stream>>>(x, dinv, sbuf, N);
    agg1_k<<<(N + 255) / 256, 256, 0, stream>>>(sbuf, offs, csr, dinv, tbuf, N);

    // --- layer 2 (fused rank-1 expand + GEMM) ---
    gemm_rank1_k<<<(N + 127) / 128, 256, 0, stream>>>(tbuf, W1, b1, W2, dinv, B, N);
    aggregate_k<<<(N + 3) / 4, 256, 0, stream>>>(B, offs, csr, dinv, b2, A, N);

    // --- layer 3 ---
    gemm_k<<<(N + 127) / 128, 256, 0, stream>>>(A, W3, nullptr, dinv, B, N, 0);
    agg_pool_k<<<(N + 127) / 128, 256, 0, stream>>>(B, offs, csr, dinv, b3, batch, P, N);

    // --- fused MLP head ---
    head_k<<<(G + 127) / 128, 256, 0, stream>>>(P, batch, Wl1, bl1, Wl2, bl2, Wl3, bl3,
                                                (float*)d_out, N, G);
}